// Round 3
// baseline (876.937 us; speedup 1.0000x reference)
//
#include <hip/hip_runtime.h>
#include <hip/hip_cooperative_groups.h>
#include <hip/hip_bf16.h>
#include <math.h>

namespace cg = cooperative_groups;

// ---------------- problem constants ----------------
#define B_SZ 2048
#define D_SZ 1024
#define U_SZ 1024
#define L_SZ 3
#define NB 8
#define KAN_K (D_SZ + D_SZ * NB)     // 9216
#define KAN_N (L_SZ * U_SZ)          // 3072
#define LSTM_K (D_SZ + U_SZ)         // 2048
#define COMB_K (U_SZ + L_SZ * U_SZ)  // 4096
#define LSTM_N (4 * U_SZ)            // 4096

// job counts
#define P1_JOBS 18176   // 8192 prep + 9984 transpose
#define P2_JOBS 1280    // 768 KAN (72 iters, first) + 512 LSTM (32 iters)
#define P3_JOBS 14336   // 8192 gates + 6144 kan-reduce
#define P4_JOBS 512     // combine split-K=4
#define P5_JOBS 2048    // combine reduce

typedef __attribute__((ext_vector_type(8))) short bhalf8_t;
typedef __attribute__((ext_vector_type(4))) float floatx4_t;

__device__ inline void async_copy16(const void* g, void* l) {
  __builtin_amdgcn_global_load_lds(
      (const __attribute__((address_space(1))) void*)g,
      (__attribute__((address_space(3))) void*)l, 16, 0, 0);
}

__device__ inline float fsig(float v) { return 1.f / (1.f + __expf(-v)); }
__device__ inline float ftanh(float v) { return 1.f - 2.f / (__expf(2.f * v) + 1.f); }
__device__ inline unsigned short bfb(float v) {
  __hip_bfloat16 h = __float2bfloat16(v);
  return *(unsigned short*)&h;
}

// ---- GEMM tile core (verified rounds 1-2: zero bank conflicts) ----
// C[m0:+128, n0:+128] = A[m0:+128, kBeg:kEnd] * Bt[n0:+128, kBeg:kEnd]^T
__device__ __forceinline__ void gemm_core(
    const __hip_bfloat16* __restrict__ A, const __hip_bfloat16* __restrict__ Bt,
    int lda, float* __restrict__ C, int ldc, int m0, int n0, int kBeg, int kEnd,
    char* lds) {
  char* ldsA = lds;
  char* ldsB = lds + 16384;
  int tid = threadIdx.x;
  int lane = tid & 63;
  int wave = tid >> 6;
  int wm = wave >> 1, wn = wave & 1;
  int q = lane >> 4, l16 = lane & 15;

  floatx4_t acc[4][4];
#pragma unroll
  for (int i = 0; i < 4; ++i)
#pragma unroll
    for (int j = 0; j < 4; ++j) acc[i][j] = (floatx4_t){0.f, 0.f, 0.f, 0.f};

  const __hip_bfloat16* Ab = A + (size_t)m0 * lda;
  const __hip_bfloat16* Bb = Bt + (size_t)n0 * lda;

  for (int k0 = kBeg; k0 < kEnd; k0 += 64) {
#pragma unroll
    for (int it = 0; it < 4; ++it) {
      int L = tid + it * 256;
      int n = L >> 3;
      int c = (L & 7) ^ (n & 7);
      async_copy16((const char*)(Ab + (size_t)n * lda + k0) + c * 16, ldsA + L * 16);
    }
#pragma unroll
    for (int it = 0; it < 4; ++it) {
      int L = tid + it * 256;
      int n = L >> 3;
      int c = (L & 7) ^ (n & 7);
      async_copy16((const char*)(Bb + (size_t)n * lda + k0) + c * 16, ldsB + L * 16);
    }
    __syncthreads();
#pragma unroll
    for (int s = 0; s < 2; ++s) {
      bhalf8_t af[4], bf[4];
#pragma unroll
      for (int mt = 0; mt < 4; ++mt) {
        int row = wm * 64 + mt * 16 + l16;
        int p = (s * 4 + q) ^ (row & 7);
        af[mt] = *(const bhalf8_t*)(ldsA + row * 128 + p * 16);
      }
#pragma unroll
      for (int nt = 0; nt < 4; ++nt) {
        int row = wn * 64 + nt * 16 + l16;
        int p = (s * 4 + q) ^ (row & 7);
        bf[nt] = *(const bhalf8_t*)(ldsB + row * 128 + p * 16);
      }
#pragma unroll
      for (int mt = 0; mt < 4; ++mt)
#pragma unroll
        for (int nt = 0; nt < 4; ++nt)
          acc[mt][nt] = __builtin_amdgcn_mfma_f32_16x16x32_bf16(af[mt], bf[nt], acc[mt][nt], 0, 0, 0);
    }
    __syncthreads();
  }
#pragma unroll
  for (int mt = 0; mt < 4; ++mt) {
#pragma unroll
    for (int nt = 0; nt < 4; ++nt) {
      int ccol = n0 + wn * 64 + nt * 16 + l16;
#pragma unroll
      for (int i = 0; i < 4; ++i) {
        int crow = m0 + wm * 64 + mt * 16 + q * 4 + i;
        C[(size_t)crow * ldc + ccol] = acc[mt][nt][i];
      }
    }
  }
}

// =================================================================
// ONE cooperative persistent kernel; phases separated by grid.sync()
// =================================================================
__global__ __launch_bounds__(256, 3) void fused_all(
    const float* x, const float* h_prev, const float* c_prev,
    const float* lstm_k, const float* lstm_r, const float* lstm_b,
    const float* base_w, const float* spline_w, const float* comb_w,
    const float* comb_b,
    __hip_bfloat16* A1, __hip_bfloat16* Akan, __hip_bfloat16* Acomb,
    __hip_bfloat16* Bt1, __hip_bfloat16* Btk, __hip_bfloat16* Btc,
    float* z, float* Pkan, float* out, int* ctr) {
  __shared__ __align__(16) char smem[32768];
  __shared__ int jid;
  cg::grid_group grid = cg::this_grid();
  int tid = threadIdx.x;

  // ---------------- Phase 1: prep + weight transposes ----------------
  if (blockIdx.x == 0 && tid == 0) *ctr = 0;  // zero P2 work-queue counter
  for (int job = blockIdx.x; job < P1_JOBS; job += gridDim.x) {
    if (job < 8192) {
      // prep: bf16 casts + silu + B-spline bases
      int idx = job * 256 + tid;  // over B*D
      int b = idx >> 10, d = idx & 1023;
      float xv = x[idx];
      float hv = h_prev[idx];
      A1[(size_t)b * LSTM_K + d] = __float2bfloat16(xv);
      A1[(size_t)b * LSTM_K + D_SZ + d] = __float2bfloat16(hv);
      float sg = 1.0f / (1.0f + __expf(-xv));
      Akan[(size_t)b * KAN_K + d] = __float2bfloat16(xv * sg);
      float t[12];
#pragma unroll
      for (int i = 0; i < 12; ++i) t[i] = (float)(-1.0 + 0.4 * (double)(i - 3));
      float bb[11];
#pragma unroll
      for (int j = 0; j < 11; ++j) bb[j] = (xv >= t[j] && xv < t[j + 1]) ? 1.0f : 0.0f;
#pragma unroll
      for (int p = 1; p <= 3; ++p) {
#pragma unroll
        for (int j = 0; j + p < 11; ++j) {
          float invl = 1.0f / (t[j + p] - t[j]);          // compile-time folded
          float invr = 1.0f / (t[j + p + 1] - t[j + 1]);  // compile-time folded
          bb[j] = (xv - t[j]) * invl * bb[j] + (t[j + p + 1] - xv) * invr * bb[j + 1];
        }
      }
      unsigned short o[8];
#pragma unroll
      for (int j = 0; j < 8; ++j) o[j] = bfb(bb[j]);
      *(uint4*)(Akan + (size_t)b * KAN_K + D_SZ + d * 8) = *(uint4*)o;
    } else {
      // transpose f32 [K,N] -> bf16 [N,K], 64x64 tile per job
      int id = job - 8192;
      const float* src;
      __hip_bfloat16* dst;
      int srcLd, dstLd, gxs;
      if (id < 1024) {
        src = lstm_k; dst = Bt1; srcLd = 4096; dstLd = 2048; gxs = 6;
      } else if (id < 2048) {
        id -= 1024; src = lstm_r; dst = Bt1 + 1024; srcLd = 4096; dstLd = 2048; gxs = 6;
      } else if (id < 3072) {
        id -= 2048; src = comb_w; dst = Btc; srcLd = 1024; dstLd = 4096; gxs = 4;
      } else if (id < 3840) {
        id -= 3072; int l = id >> 8; id &= 255;
        src = base_w + (size_t)l * 1048576;
        dst = Btk + (size_t)l * U_SZ * KAN_K;
        srcLd = 1024; dstLd = KAN_K; gxs = 4;
      } else {
        id -= 3840; int l = id >> 11; id &= 2047;
        src = spline_w + (size_t)l * 8388608;
        dst = Btk + (size_t)l * U_SZ * KAN_K + D_SZ;
        srcLd = 1024; dstLd = KAN_K; gxs = 4;
      }
      int n0 = (id & ((1 << gxs) - 1)) * 64;
      int k0 = (id >> gxs) * 64;
      float (*tile)[65] = (float(*)[65])smem;
      int tx = tid & 63;
      int ty = tid >> 6;
#pragma unroll
      for (int i = 0; i < 16; ++i) {
        int r = ty + i * 4;
        tile[r][tx] = src[(size_t)(k0 + r) * srcLd + n0 + tx];
      }
      __syncthreads();
      // vectorized 8B stores: thread covers n=(tid>>4)+16i, k=(tid&15)*4..+3
      int kg = (tid & 15) * 4;
      int nn = tid >> 4;
#pragma unroll
      for (int i = 0; i < 4; ++i) {
        int n = nn + i * 16;
        ushort4 w;
        w.x = bfb(tile[kg + 0][n]);
        w.y = bfb(tile[kg + 1][n]);
        w.z = bfb(tile[kg + 2][n]);
        w.w = bfb(tile[kg + 3][n]);
        *(ushort4*)(dst + (size_t)(n0 + n) * dstLd + k0 + kg) = w;
      }
      __syncthreads();  // protect tile before next job's writes
    }
  }
  grid.sync();

  // ---------------- Phase 2: LSTM + KAN GEMMs, dynamic queue ----------------
  // jobs 0..767: KAN split-K=2 (72 iters each, longest-first)
  // jobs 768..1279: LSTM (32 iters each)
  for (;;) {
    if (tid == 0) jid = atomicAdd(ctr, 1);
    __syncthreads();
    int j = jid;
    if (j >= P2_JOBS) break;
    if (j < 768) {
      int sk = j >= 384;
      int rem = j - sk * 384;
      int n0 = (rem % 24) * 128;
      int m0 = (rem / 24) * 128;
      gemm_core(Akan, Btk, KAN_K, Pkan + (size_t)sk * B_SZ * KAN_N, KAN_N,
                m0, n0, sk * 4608, (sk + 1) * 4608, smem);
    } else {
      int j2 = j - 768;
      int n0 = (j2 & 31) * 128;
      int m0 = (j2 >> 5) * 128;
      gemm_core(A1, Bt1, LSTM_K, z, LSTM_N, m0, n0, 0, LSTM_K, smem);
    }
  }
  grid.sync();

  // ---------------- Phase 3: gates + KAN split-K reduce ----------------
  float* h_out = out + (size_t)B_SZ * U_SZ;
  float* c_out = out + 2 * (size_t)B_SZ * U_SZ;
  for (int job = blockIdx.x; job < P3_JOBS; job += gridDim.x) {
    if (job < 8192) {
      int idx = job * 256 + tid;  // over B*U
      int b = idx >> 10, u = idx & 1023;
      const float* zr = z + (size_t)b * LSTM_N;
      float zi = zr[u] + lstm_b[u];
      float zf = zr[U_SZ + u] + lstm_b[U_SZ + u];
      float zg = zr[2 * U_SZ + u] + lstm_b[2 * U_SZ + u];
      float zo = zr[3 * U_SZ + u] + lstm_b[3 * U_SZ + u];
      float c = fsig(zf) * c_prev[idx] + fsig(zi) * ftanh(zg);
      float h = fsig(zo) * ftanh(c);
      h_out[idx] = h;
      c_out[idx] = c;
      Acomb[(size_t)b * COMB_K + u] = __float2bfloat16(h);
    } else {
      int g = (job - 8192) * 256 + tid;  // over B*KAN_N/4
      int m = g / (KAN_N / 4);
      int c4 = (g - m * (KAN_N / 4)) * 4;
      const float4 p0 = *(const float4*)(Pkan + (size_t)m * KAN_N + c4);
      const float4 p1 = *(const float4*)(Pkan + (size_t)B_SZ * KAN_N + (size_t)m * KAN_N + c4);
      ushort4 o;
      o.x = bfb(p0.x + p1.x);
      o.y = bfb(p0.y + p1.y);
      o.z = bfb(p0.z + p1.z);
      o.w = bfb(p0.w + p1.w);
      *(ushort4*)(Acomb + (size_t)m * COMB_K + U_SZ + c4) = o;
    }
  }
  grid.sync();

  // ---------------- Phase 4: combine GEMM split-K=4 (Pcomb aliases Pkan) ----
  for (int j = blockIdx.x; j < P4_JOBS; j += gridDim.x) {
    int sk = j >> 7;
    int rem = j & 127;
    int n0 = (rem & 7) * 128;
    int m0 = (rem >> 3) * 128;
    gemm_core(Acomb, Btc, COMB_K, Pkan + (size_t)sk * B_SZ * U_SZ, U_SZ,
              m0, n0, sk * 1024, (sk + 1) * 1024, smem);
  }
  grid.sync();

  // ---------------- Phase 5: combine reduce + bias ----------------
  for (int g0 = blockIdx.x; g0 < P5_JOBS; g0 += gridDim.x) {
    int g = g0 * 256 + tid;  // over B*U/4
    int m = g >> 8;
    int c4 = (g & 255) * 4;
    float4 s = *(const float4*)(Pkan + (size_t)m * U_SZ + c4);
    const size_t stride = (size_t)B_SZ * U_SZ;
#pragma unroll
    for (int p = 1; p < 4; ++p) {
      float4 t = *(const float4*)(Pkan + stride * p + (size_t)m * U_SZ + c4);
      s.x += t.x; s.y += t.y; s.z += t.z; s.w += t.w;
    }
    float4 bv = *(const float4*)(comb_b + c4);
    s.x += bv.x; s.y += bv.y; s.z += bv.z; s.w += bv.w;
    *(float4*)(out + (size_t)m * U_SZ + c4) = s;
  }
}

// ---------------- launcher ----------------
extern "C" void kernel_launch(void* const* d_in, const int* in_sizes, int n_in,
                              void* d_out, int out_size, void* d_ws, size_t ws_size,
                              hipStream_t stream) {
  const float* x        = (const float*)d_in[0];
  const float* h_prev   = (const float*)d_in[1];
  const float* c_prev   = (const float*)d_in[2];
  const float* lstm_k   = (const float*)d_in[3];
  const float* lstm_r   = (const float*)d_in[4];
  const float* lstm_b   = (const float*)d_in[5];
  const float* base_w   = (const float*)d_in[6];
  const float* spline_w = (const float*)d_in[7];
  const float* comb_w   = (const float*)d_in[8];
  const float* comb_b   = (const float*)d_in[9];
  float* out = (float*)d_out;

  char* ws = (char*)d_ws;
  auto alloc = [&](size_t bytes) {
    char* p = ws;
    ws += (bytes + 255) & ~(size_t)255;
    return p;
  };
  __hip_bfloat16* A1    = (__hip_bfloat16*)alloc((size_t)B_SZ * LSTM_K * 2);
  __hip_bfloat16* Akan  = (__hip_bfloat16*)alloc((size_t)B_SZ * KAN_K * 2);
  __hip_bfloat16* Acomb = (__hip_bfloat16*)alloc((size_t)B_SZ * COMB_K * 2);
  __hip_bfloat16* Bt1   = (__hip_bfloat16*)alloc((size_t)LSTM_N * LSTM_K * 2);
  __hip_bfloat16* Btk   = (__hip_bfloat16*)alloc((size_t)KAN_N * KAN_K * 2);
  __hip_bfloat16* Btc   = (__hip_bfloat16*)alloc((size_t)U_SZ * COMB_K * 2);
  float* z              = (float*)alloc((size_t)B_SZ * LSTM_N * 4);
  float* Pkan           = (float*)alloc((size_t)2 * B_SZ * KAN_N * 4);  // also Pcomb (33.5MB <= 50.3MB)
  int* ctr              = (int*)alloc(256);

  int nb = 0;
  if (hipOccupancyMaxActiveBlocksPerMultiprocessor(&nb, (const void*)fused_all, 256, 0) != hipSuccess || nb < 1)
    nb = 2;
  int gridBlocks = nb * 256;  // 256 CUs on MI355X
  if (gridBlocks > 768) gridBlocks = 768;

  void* args[] = {
      (void*)&x, (void*)&h_prev, (void*)&c_prev, (void*)&lstm_k, (void*)&lstm_r,
      (void*)&lstm_b, (void*)&base_w, (void*)&spline_w, (void*)&comb_w, (void*)&comb_b,
      (void*)&A1, (void*)&Akan, (void*)&Acomb, (void*)&Bt1, (void*)&Btk, (void*)&Btc,
      (void*)&z, (void*)&Pkan, (void*)&out, (void*)&ctr};
  hipLaunchCooperativeKernel((const void*)fused_all, dim3(gridBlocks), dim3(256),
                             args, 0, stream);
}

// Round 4
// 510.092 us; speedup vs baseline: 1.7192x; 1.7192x over previous
//
#include <hip/hip_runtime.h>
#include <hip/hip_bf16.h>
#include <math.h>

// ---------------- problem constants ----------------
#define B_SZ 2048
#define D_SZ 1024
#define U_SZ 1024
#define L_SZ 3
#define NB 8
#define KAN_K (D_SZ + D_SZ * NB)     // 9216
#define KAN_N (L_SZ * U_SZ)          // 3072
#define LSTM_K (D_SZ + U_SZ)         // 2048
#define COMB_K (U_SZ + L_SZ * U_SZ)  // 4096
#define LSTM_N (4 * U_SZ)            // 4096

typedef __attribute__((ext_vector_type(8))) short bhalf8_t;  // 8 bf16 in 4 VGPRs
typedef __attribute__((ext_vector_type(4))) float floatx4_t; // MFMA C/D

__device__ inline void async_copy16(const void* g, void* l) {
  __builtin_amdgcn_global_load_lds(
      (const __attribute__((address_space(1))) void*)g,
      (__attribute__((address_space(3))) void*)l, 16, 0, 0);
}

__device__ inline float fsig(float v) { return 1.f / (1.f + __expf(-v)); }
__device__ inline float ftanh(float v) { return 1.f - 2.f / (__expf(2.f * v) + 1.f); }
__device__ inline unsigned short bfb(float v) {
  __hip_bfloat16 h = __float2bfloat16(v);
  return *(unsigned short*)&h;
}

// =================================================================
// Kernel 1: prep (bf16 casts + silu + bases) fused with ALL weight
// transposes (f32 [K,N] -> bf16 [N,K]); one job per block (max TLP —
// round-3 lesson: do NOT cap memory phases at GEMM occupancy).
// Blocks: [0,8192) prep over B*D; [8192,18176) transpose 64x64 tiles.
// =================================================================
__global__ __launch_bounds__(256) void prep_trans(
    const float* __restrict__ x, const float* __restrict__ h_prev,
    const float* __restrict__ lstm_k, const float* __restrict__ lstm_r,
    const float* __restrict__ comb_w, const float* __restrict__ base_w,
    const float* __restrict__ spline_w,
    __hip_bfloat16* __restrict__ A1, __hip_bfloat16* __restrict__ Akan,
    __hip_bfloat16* __restrict__ Bt1, __hip_bfloat16* __restrict__ Btc,
    __hip_bfloat16* __restrict__ Btk) {
  __shared__ float tile[64][65];
  int bid = blockIdx.x;
  int tid = threadIdx.x;
  if (bid < 8192) {
    // ---- prep path ----
    int idx = bid * 256 + tid;  // over B*D
    int b = idx >> 10, d = idx & 1023;
    float xv = x[idx];
    float hv = h_prev[idx];
    A1[(size_t)b * LSTM_K + d] = __float2bfloat16(xv);
    A1[(size_t)b * LSTM_K + D_SZ + d] = __float2bfloat16(hv);
    float sg = 1.0f / (1.0f + __expf(-xv));
    Akan[(size_t)b * KAN_K + d] = __float2bfloat16(xv * sg);
    float t[12];
#pragma unroll
    for (int i = 0; i < 12; ++i) t[i] = (float)(-1.0 + 0.4 * (double)(i - 3));
    float bb[11];
#pragma unroll
    for (int j = 0; j < 11; ++j) bb[j] = (xv >= t[j] && xv < t[j + 1]) ? 1.0f : 0.0f;
#pragma unroll
    for (int p = 1; p <= 3; ++p) {
#pragma unroll
      for (int j = 0; j + p < 11; ++j) {
        float invl = 1.0f / (t[j + p] - t[j]);          // compile-time folded
        float invr = 1.0f / (t[j + p + 1] - t[j + 1]);  // compile-time folded
        bb[j] = (xv - t[j]) * invl * bb[j] + (t[j + p + 1] - xv) * invr * bb[j + 1];
      }
    }
    unsigned short o[8];
#pragma unroll
    for (int j = 0; j < 8; ++j) o[j] = bfb(bb[j]);
    *(uint4*)(Akan + (size_t)b * KAN_K + D_SZ + d * 8) = *(uint4*)o;
    return;
  }
  // ---- transpose path ----
  int id = bid - 8192;
  const float* src;
  __hip_bfloat16* dst;
  int srcLd, dstLd, gxs;
  if (id < 1024) {            // lstm_kernel [1024,4096] -> Bt1[:,0:1024]
    src = lstm_k; dst = Bt1; srcLd = 4096; dstLd = 2048; gxs = 6;
  } else if (id < 2048) {     // lstm_rkernel [1024,4096] -> Bt1[:,1024:2048]
    id -= 1024; src = lstm_r; dst = Bt1 + 1024; srcLd = 4096; dstLd = 2048; gxs = 6;
  } else if (id < 3072) {     // combine_w [4096,1024] -> Btc
    id -= 2048; src = comb_w; dst = Btc; srcLd = 1024; dstLd = 4096; gxs = 4;
  } else if (id < 3840) {     // base_w l: [1024,1024] -> Btk[l][:,0:1024]
    id -= 3072; int l = id >> 8; id &= 255;
    src = base_w + (size_t)l * 1048576;
    dst = Btk + (size_t)l * U_SZ * KAN_K;
    srcLd = 1024; dstLd = KAN_K; gxs = 4;
  } else {                    // spline_w l: [8192,1024] -> Btk[l][:,1024:9216]
    id -= 3840; int l = id >> 11; id &= 2047;
    src = spline_w + (size_t)l * 8388608;
    dst = Btk + (size_t)l * U_SZ * KAN_K + D_SZ;
    srcLd = 1024; dstLd = KAN_K; gxs = 4;
  }
  int n0 = (id & ((1 << gxs) - 1)) * 64;
  int k0 = (id >> gxs) * 64;
  // float4 loads: lane covers rows r0+16i, col group c4..c4+3
  int c4 = (tid & 15) * 4;
  int r0 = tid >> 4;  // 0..15
#pragma unroll
  for (int i = 0; i < 4; ++i) {
    int r = r0 + i * 16;
    const float4 v = *(const float4*)(src + (size_t)(k0 + r) * srcLd + n0 + c4);
    tile[r][c4 + 0] = v.x;
    tile[r][c4 + 1] = v.y;
    tile[r][c4 + 2] = v.z;
    tile[r][c4 + 3] = v.w;
  }
  __syncthreads();
  // ushort4 stores: lane covers n = (tid>>4)+16i, k = (tid&15)*4..+3
  int kg = (tid & 15) * 4;
  int nn = tid >> 4;
#pragma unroll
  for (int i = 0; i < 4; ++i) {
    int n = nn + i * 16;
    ushort4 w;
    w.x = bfb(tile[kg + 0][n]);
    w.y = bfb(tile[kg + 1][n]);
    w.z = bfb(tile[kg + 2][n]);
    w.w = bfb(tile[kg + 3][n]);
    *(ushort4*)(dst + (size_t)(n0 + n) * dstLd + k0 + kg) = w;
  }
}

// =================================================================
// GEMM core (verified r1/r2: zero bank conflicts):
// C[m0:+128, n0:+128] = A[m0:+128, kBeg:kEnd] * Bt[n0:+128, kBeg:kEnd]^T
// =================================================================
__device__ __forceinline__ void gemm_core(
    const __hip_bfloat16* __restrict__ A, const __hip_bfloat16* __restrict__ Bt,
    int lda, float* __restrict__ C, int ldc, int m0, int n0, int kBeg, int kEnd) {
  __shared__ __align__(16) char lds[32768];
  char* ldsA = lds;
  char* ldsB = lds + 16384;
  int tid = threadIdx.x;
  int lane = tid & 63;
  int wave = tid >> 6;
  int wm = wave >> 1, wn = wave & 1;
  int q = lane >> 4, l16 = lane & 15;

  floatx4_t acc[4][4];
#pragma unroll
  for (int i = 0; i < 4; ++i)
#pragma unroll
    for (int j = 0; j < 4; ++j) acc[i][j] = (floatx4_t){0.f, 0.f, 0.f, 0.f};

  const __hip_bfloat16* Ab = A + (size_t)m0 * lda;
  const __hip_bfloat16* Bb = Bt + (size_t)n0 * lda;

  for (int k0 = kBeg; k0 < kEnd; k0 += 64) {
#pragma unroll
    for (int it = 0; it < 4; ++it) {
      int L = tid + it * 256;
      int n = L >> 3;
      int c = (L & 7) ^ (n & 7);
      async_copy16((const char*)(Ab + (size_t)n * lda + k0) + c * 16, ldsA + L * 16);
    }
#pragma unroll
    for (int it = 0; it < 4; ++it) {
      int L = tid + it * 256;
      int n = L >> 3;
      int c = (L & 7) ^ (n & 7);
      async_copy16((const char*)(Bb + (size_t)n * lda + k0) + c * 16, ldsB + L * 16);
    }
    __syncthreads();
#pragma unroll
    for (int s = 0; s < 2; ++s) {
      bhalf8_t af[4], bf[4];
#pragma unroll
      for (int mt = 0; mt < 4; ++mt) {
        int row = wm * 64 + mt * 16 + l16;
        int p = (s * 4 + q) ^ (row & 7);
        af[mt] = *(const bhalf8_t*)(ldsA + row * 128 + p * 16);
      }
#pragma unroll
      for (int nt = 0; nt < 4; ++nt) {
        int row = wn * 64 + nt * 16 + l16;
        int p = (s * 4 + q) ^ (row & 7);
        bf[nt] = *(const bhalf8_t*)(ldsB + row * 128 + p * 16);
      }
#pragma unroll
      for (int mt = 0; mt < 4; ++mt)
#pragma unroll
        for (int nt = 0; nt < 4; ++nt)
          acc[mt][nt] = __builtin_amdgcn_mfma_f32_16x16x32_bf16(af[mt], bf[nt], acc[mt][nt], 0, 0, 0);
    }
    __syncthreads();
  }
#pragma unroll
  for (int mt = 0; mt < 4; ++mt) {
#pragma unroll
    for (int nt = 0; nt < 4; ++nt) {
      int ccol = n0 + wn * 64 + nt * 16 + l16;
#pragma unroll
      for (int i = 0; i < 4; ++i) {
        int crow = m0 + wm * 64 + mt * 16 + q * 4 + i;
        C[(size_t)crow * ldc + ccol] = acc[mt][nt][i];
      }
    }
  }
}

// =================================================================
// Kernel 2: merged LSTM + KAN GEMMs. LONG JOBS FIRST:
// blocks [0,768): KAN split-K=2 (72 iters) — fill all resident slots at t=0
// blocks [768,1280): LSTM (32 iters) — short jobs backfill, small tail.
// Makespan model: 72+32=104 iter-times vs round-2 ordering's 144.
// =================================================================
__global__ __launch_bounds__(256) void gemm_multi(
    const __hip_bfloat16* __restrict__ A1, const __hip_bfloat16* __restrict__ Bt1,
    const __hip_bfloat16* __restrict__ Akan, const __hip_bfloat16* __restrict__ Btk,
    float* __restrict__ z, float* __restrict__ Pkan) {
  int id = blockIdx.x;
  if (id < 768) {
    int sk = id >= 384;
    int rem = id - sk * 384;
    int n0 = (rem % 24) * 128;
    int m0 = (rem / 24) * 128;
    gemm_core(Akan, Btk, KAN_K, Pkan + (size_t)sk * B_SZ * KAN_N, KAN_N,
              m0, n0, sk * 4608, (sk + 1) * 4608);
  } else {
    int j2 = id - 768;
    int n0 = (j2 & 31) * 128;
    int m0 = (j2 >> 5) * 128;
    gemm_core(A1, Bt1, LSTM_K, z, LSTM_N, m0, n0, 0, LSTM_K);
  }
}

// =================================================================
// Kernel 3: fused LSTM pointwise gates + KAN split-K reduce (->bf16 Acomb)
// =================================================================
__global__ __launch_bounds__(256) void reduce_fuse(
    const float* __restrict__ z, const float* __restrict__ c_prev,
    const float* __restrict__ bias, const float* __restrict__ Pkan,
    float* __restrict__ h_out, float* __restrict__ c_out,
    __hip_bfloat16* __restrict__ Acomb) {
  int bid = blockIdx.x;
  int tid = threadIdx.x;
  if (bid < 8192) {
    int idx = bid * 256 + tid;  // over B*U
    int b = idx >> 10, u = idx & 1023;
    const float* zr = z + (size_t)b * LSTM_N;
    float zi = zr[u] + bias[u];
    float zf = zr[U_SZ + u] + bias[U_SZ + u];
    float zg = zr[2 * U_SZ + u] + bias[2 * U_SZ + u];
    float zo = zr[3 * U_SZ + u] + bias[3 * U_SZ + u];
    float c = fsig(zf) * c_prev[idx] + fsig(zi) * ftanh(zg);
    float h = fsig(zo) * ftanh(c);
    h_out[idx] = h;
    c_out[idx] = c;
    Acomb[(size_t)b * COMB_K + u] = __float2bfloat16(h);
  } else {
    int g = (bid - 8192) * 256 + tid;  // over B*KAN_N/4
    int m = g / (KAN_N / 4);
    int c4 = (g - m * (KAN_N / 4)) * 4;
    const float4 p0 = *(const float4*)(Pkan + (size_t)m * KAN_N + c4);
    const float4 p1 = *(const float4*)(Pkan + (size_t)B_SZ * KAN_N + (size_t)m * KAN_N + c4);
    ushort4 o;
    o.x = bfb(p0.x + p1.x);
    o.y = bfb(p0.y + p1.y);
    o.z = bfb(p0.z + p1.z);
    o.w = bfb(p0.w + p1.w);
    *(ushort4*)(Acomb + (size_t)m * COMB_K + U_SZ + c4) = o;
  }
}

// =================================================================
// Kernel 4: combine GEMM split-K=4 -> Pcomb partials
// =================================================================
__global__ __launch_bounds__(256) void gemm_comb(
    const __hip_bfloat16* __restrict__ Acomb, const __hip_bfloat16* __restrict__ Btc,
    float* __restrict__ Pcomb) {
  int id = blockIdx.x;
  int sk = id >> 7;
  int rem = id & 127;
  int n0 = (rem & 7) * 128;
  int m0 = (rem >> 3) * 128;
  gemm_core(Acomb, Btc, COMB_K, Pcomb + (size_t)sk * B_SZ * U_SZ, U_SZ,
            m0, n0, sk * 1024, (sk + 1) * 1024);
}

// Kernel 5: reduce 4 combine partials + bias -> out (f32)
__global__ __launch_bounds__(256) void comb_reduce(
    const float* __restrict__ Pcomb, const float* __restrict__ bias,
    float* __restrict__ out) {
  int g = blockIdx.x * 256 + threadIdx.x;  // over B*U/4
  int m = g >> 8;
  int c4 = (g & 255) * 4;
  float4 s = *(const float4*)(Pcomb + (size_t)m * U_SZ + c4);
  const size_t stride = (size_t)B_SZ * U_SZ;
#pragma unroll
  for (int p = 1; p < 4; ++p) {
    float4 t = *(const float4*)(Pcomb + stride * p + (size_t)m * U_SZ + c4);
    s.x += t.x; s.y += t.y; s.z += t.z; s.w += t.w;
  }
  float4 bv = *(const float4*)(bias + c4);
  s.x += bv.x; s.y += bv.y; s.z += bv.z; s.w += bv.w;
  *(float4*)(out + (size_t)m * U_SZ + c4) = s;
}

// ---------------- launcher ----------------
extern "C" void kernel_launch(void* const* d_in, const int* in_sizes, int n_in,
                              void* d_out, int out_size, void* d_ws, size_t ws_size,
                              hipStream_t stream) {
  const float* x        = (const float*)d_in[0];
  const float* h_prev   = (const float*)d_in[1];
  const float* c_prev   = (const float*)d_in[2];
  const float* lstm_k   = (const float*)d_in[3];
  const float* lstm_r   = (const float*)d_in[4];
  const float* lstm_b   = (const float*)d_in[5];
  const float* base_w   = (const float*)d_in[6];
  const float* spline_w = (const float*)d_in[7];
  const float* comb_w   = (const float*)d_in[8];
  const float* comb_b   = (const float*)d_in[9];
  float* out = (float*)d_out;  // [output | h | c], each B*U f32

  char* ws = (char*)d_ws;
  auto alloc = [&](size_t bytes) {
    char* p = ws;
    ws += (bytes + 255) & ~(size_t)255;
    return p;
  };
  __hip_bfloat16* A1    = (__hip_bfloat16*)alloc((size_t)B_SZ * LSTM_K * 2);
  __hip_bfloat16* Akan  = (__hip_bfloat16*)alloc((size_t)B_SZ * KAN_K * 2);
  __hip_bfloat16* Acomb = (__hip_bfloat16*)alloc((size_t)B_SZ * COMB_K * 2);
  __hip_bfloat16* Bt1   = (__hip_bfloat16*)alloc((size_t)LSTM_N * LSTM_K * 2);
  __hip_bfloat16* Btk   = (__hip_bfloat16*)alloc((size_t)KAN_N * KAN_K * 2);
  __hip_bfloat16* Btc   = (__hip_bfloat16*)alloc((size_t)U_SZ * COMB_K * 2);
  float* z              = (float*)alloc((size_t)B_SZ * LSTM_N * 4);
  float* Pkan           = (float*)alloc((size_t)2 * B_SZ * KAN_N * 4);
  float* Pcomb          = Pkan;  // alias: Pkan dead after reduce_fuse (50.3MB >= 33.5MB)

  prep_trans<<<dim3(18176), 256, 0, stream>>>(x, h_prev, lstm_k, lstm_r, comb_w,
                                              base_w, spline_w, A1, Akan, Bt1, Btc, Btk);
  gemm_multi<<<dim3(1280), 256, 0, stream>>>(A1, Bt1, Akan, Btk, z, Pkan);
  reduce_fuse<<<dim3(14336), 256, 0, stream>>>(z, c_prev, lstm_b, Pkan,
                                               out + (size_t)B_SZ * U_SZ,
                                               out + 2 * (size_t)B_SZ * U_SZ, Acomb);
  gemm_comb<<<dim3(512), 256, 0, stream>>>(Acomb, Btc, Pcomb);
  comb_reduce<<<dim3(2048), 256, 0, stream>>>(Pcomb, comb_b, out);
}

// Round 5
// 495.204 us; speedup vs baseline: 1.7709x; 1.0301x over previous
//
#include <hip/hip_runtime.h>
#include <hip/hip_bf16.h>
#include <math.h>

// ---------------- problem constants ----------------
#define B_SZ 2048
#define D_SZ 1024
#define U_SZ 1024
#define L_SZ 3
#define NB 8
#define KAN_K (D_SZ + D_SZ * NB)     // 9216 (kk dim)
#define WCAT_K (L_SZ * U_SZ)         // 3072 (fused inner dim)
#define LSTM_K (D_SZ + U_SZ)         // 2048
#define LSTM_N (4 * U_SZ)            // 4096
#define COMB_K (U_SZ + L_SZ * U_SZ)  // 4096

typedef __attribute__((ext_vector_type(8))) short bhalf8_t;  // 8 bf16 in 4 VGPRs
typedef __attribute__((ext_vector_type(4))) float floatx4_t; // MFMA C/D

__device__ inline void async_copy16(const void* g, void* l) {
  __builtin_amdgcn_global_load_lds(
      (const __attribute__((address_space(1))) void*)g,
      (__attribute__((address_space(3))) void*)l, 16, 0, 0);
}

__device__ inline float fsig(float v) { return 1.f / (1.f + __expf(-v)); }
__device__ inline float ftanh(float v) { return 1.f - 2.f / (__expf(2.f * v) + 1.f); }
__device__ inline unsigned short bfb(float v) {
  __hip_bfloat16 h = __float2bfloat16(v);
  return *(unsigned short*)&h;
}
__device__ inline unsigned int bfb2(float lo, float hi) {
  return (unsigned int)bfb(lo) | ((unsigned int)bfb(hi) << 16);
}

// =================================================================
// Kernel 1: prep + small transposes + Wcat interleave-convert.
// jobs: [0,8192) prep over B*D
//       [8192,9216)   lstm_kernel  [1024,4096] -> Bt1[:,0:1024]
//       [9216,10240)  lstm_rkernel [1024,4096] -> Bt1[:,1024:2048]
//       [10240,11264) combine_w    [4096,1024] -> Btc [1024,4096]
//       [11264,25088) Wcat[kk, l*1024+u] = bf16(Wkan_l[kk,u]) (elementwise!)
// =================================================================
__global__ __launch_bounds__(256) void prep_trans(
    const float* __restrict__ x, const float* __restrict__ h_prev,
    const float* __restrict__ lstm_k, const float* __restrict__ lstm_r,
    const float* __restrict__ comb_w, const float* __restrict__ base_w,
    const float* __restrict__ spline_w,
    __hip_bfloat16* __restrict__ A1, __hip_bfloat16* __restrict__ Akan,
    __hip_bfloat16* __restrict__ Bt1, __hip_bfloat16* __restrict__ Btc,
    __hip_bfloat16* __restrict__ Wcat) {
  __shared__ float tile[64][65];
  int bid = blockIdx.x;
  int tid = threadIdx.x;
  if (bid < 8192) {
    // ---- prep: bf16 casts + silu + B-spline bases ----
    int idx = bid * 256 + tid;  // over B*D
    int b = idx >> 10, d = idx & 1023;
    float xv = x[idx];
    float hv = h_prev[idx];
    A1[(size_t)b * LSTM_K + d] = __float2bfloat16(xv);
    A1[(size_t)b * LSTM_K + D_SZ + d] = __float2bfloat16(hv);
    float sg = 1.0f / (1.0f + __expf(-xv));
    Akan[(size_t)b * KAN_K + d] = __float2bfloat16(xv * sg);
    float t[12];
#pragma unroll
    for (int i = 0; i < 12; ++i) t[i] = (float)(-1.0 + 0.4 * (double)(i - 3));
    float bb[11];
#pragma unroll
    for (int j = 0; j < 11; ++j) bb[j] = (xv >= t[j] && xv < t[j + 1]) ? 1.0f : 0.0f;
#pragma unroll
    for (int p = 1; p <= 3; ++p) {
#pragma unroll
      for (int j = 0; j + p < 11; ++j) {
        float invl = 1.0f / (t[j + p] - t[j]);          // compile-time folded
        float invr = 1.0f / (t[j + p + 1] - t[j + 1]);  // compile-time folded
        bb[j] = (xv - t[j]) * invl * bb[j] + (t[j + p + 1] - xv) * invr * bb[j + 1];
      }
    }
    unsigned short o[8];
#pragma unroll
    for (int j = 0; j < 8; ++j) o[j] = bfb(bb[j]);
    *(uint4*)(Akan + (size_t)b * KAN_K + D_SZ + d * 8) = *(uint4*)o;
    return;
  }
  if (bid >= 11264) {
    // ---- Wcat interleave: coalesced elementwise f32->bf16 ----
    int e0 = (bid - 11264) * 2048 + tid * 8;  // 8 elems/thread
    int kk = e0 / WCAT_K;
    int col = e0 - kk * WCAT_K;
    int l = col >> 10, u = col & 1023;
    const float* srow = (kk < 1024)
        ? base_w + ((size_t)l << 20) + (size_t)kk * 1024 + u
        : spline_w + (size_t)l * 8388608 + (size_t)(kk - 1024) * 1024 + u;
    float4 v0 = *(const float4*)(srow);
    float4 v1 = *(const float4*)(srow + 4);
    uint4 q;
    q.x = bfb2(v0.x, v0.y);
    q.y = bfb2(v0.z, v0.w);
    q.z = bfb2(v1.x, v1.y);
    q.w = bfb2(v1.z, v1.w);
    *(uint4*)(Wcat + (size_t)kk * WCAT_K + col) = q;
    return;
  }
  // ---- transpose path (small weights only) ----
  int id = bid - 8192;
  const float* src;
  __hip_bfloat16* dst;
  int srcLd, dstLd, gxs;
  if (id < 1024) {            // lstm_kernel -> Bt1[:,0:1024]
    src = lstm_k; dst = Bt1; srcLd = 4096; dstLd = 2048; gxs = 6;
  } else if (id < 2048) {     // lstm_rkernel -> Bt1[:,1024:2048]
    id -= 1024; src = lstm_r; dst = Bt1 + 1024; srcLd = 4096; dstLd = 2048; gxs = 6;
  } else {                    // combine_w [4096,1024] -> Btc [1024,4096]
    id -= 2048; src = comb_w; dst = Btc; srcLd = 1024; dstLd = 4096; gxs = 4;
  }
  int n0 = (id & ((1 << gxs) - 1)) * 64;
  int k0 = (id >> gxs) * 64;
  int c4 = (tid & 15) * 4;
  int r0 = tid >> 4;
#pragma unroll
  for (int i = 0; i < 4; ++i) {
    int r = r0 + i * 16;
    const float4 v = *(const float4*)(src + (size_t)(k0 + r) * srcLd + n0 + c4);
    tile[r][c4 + 0] = v.x;
    tile[r][c4 + 1] = v.y;
    tile[r][c4 + 2] = v.z;
    tile[r][c4 + 3] = v.w;
  }
  __syncthreads();
  int kg = (tid & 15) * 4;
  int nn = tid >> 4;
#pragma unroll
  for (int i = 0; i < 4; ++i) {
    int n = nn + i * 16;
    ushort4 w;
    w.x = bfb(tile[kg + 0][n]);
    w.y = bfb(tile[kg + 1][n]);
    w.z = bfb(tile[kg + 2][n]);
    w.w = bfb(tile[kg + 3][n]);
    *(ushort4*)(dst + (size_t)(n0 + n) * dstLd + k0 + kg) = w;
  }
}

// =================================================================
// GEMM core (r1-r4 verified: zero bank conflicts). Separate lda/ldb.
// EPI: 0 = f32 store, 1 = bf16 store, 3 = f32 + bias + sum of 6 partials
// =================================================================
template <int EPI>
__device__ __forceinline__ void gemm_core(
    const __hip_bfloat16* __restrict__ A, int lda,
    const __hip_bfloat16* __restrict__ Bt, int ldb,
    void* __restrict__ Cout, int ldc, int m0, int n0, int kBeg, int kEnd,
    const float* __restrict__ bias = nullptr,
    const float* __restrict__ red = nullptr, size_t redStride = 0) {
  __shared__ __align__(16) char lds[32768];
  char* ldsA = lds;
  char* ldsB = lds + 16384;
  int tid = threadIdx.x;
  int lane = tid & 63;
  int wave = tid >> 6;
  int wm = wave >> 1, wn = wave & 1;
  int q = lane >> 4, l16 = lane & 15;

  floatx4_t acc[4][4];
#pragma unroll
  for (int i = 0; i < 4; ++i)
#pragma unroll
    for (int j = 0; j < 4; ++j) acc[i][j] = (floatx4_t){0.f, 0.f, 0.f, 0.f};

  const __hip_bfloat16* Ab = A + (size_t)m0 * lda;
  const __hip_bfloat16* Bb = Bt + (size_t)n0 * ldb;

  for (int k0 = kBeg; k0 < kEnd; k0 += 64) {
#pragma unroll
    for (int it = 0; it < 4; ++it) {
      int L = tid + it * 256;
      int n = L >> 3;
      int c = (L & 7) ^ (n & 7);
      async_copy16((const char*)(Ab + (size_t)n * lda + k0) + c * 16, ldsA + L * 16);
    }
#pragma unroll
    for (int it = 0; it < 4; ++it) {
      int L = tid + it * 256;
      int n = L >> 3;
      int c = (L & 7) ^ (n & 7);
      async_copy16((const char*)(Bb + (size_t)n * ldb + k0) + c * 16, ldsB + L * 16);
    }
    __syncthreads();
#pragma unroll
    for (int s = 0; s < 2; ++s) {
      bhalf8_t af[4], bf[4];
#pragma unroll
      for (int mt = 0; mt < 4; ++mt) {
        int row = wm * 64 + mt * 16 + l16;
        int p = (s * 4 + q) ^ (row & 7);
        af[mt] = *(const bhalf8_t*)(ldsA + row * 128 + p * 16);
      }
#pragma unroll
      for (int nt = 0; nt < 4; ++nt) {
        int row = wn * 64 + nt * 16 + l16;
        int p = (s * 4 + q) ^ (row & 7);
        bf[nt] = *(const bhalf8_t*)(ldsB + row * 128 + p * 16);
      }
#pragma unroll
      for (int mt = 0; mt < 4; ++mt)
#pragma unroll
        for (int nt = 0; nt < 4; ++nt)
          acc[mt][nt] = __builtin_amdgcn_mfma_f32_16x16x32_bf16(af[mt], bf[nt], acc[mt][nt], 0, 0, 0);
    }
    __syncthreads();
  }
  // epilogue: C/D layout col=lane&15, row=(lane>>4)*4+reg
#pragma unroll
  for (int mt = 0; mt < 4; ++mt) {
#pragma unroll
    for (int nt = 0; nt < 4; ++nt) {
      int ccol = n0 + wn * 64 + nt * 16 + l16;
#pragma unroll
      for (int i = 0; i < 4; ++i) {
        int crow = m0 + wm * 64 + mt * 16 + q * 4 + i;
        float v = acc[mt][nt][i];
        if (EPI == 0) {
          ((float*)Cout)[(size_t)crow * ldc + ccol] = v;
        } else if (EPI == 1) {
          ((__hip_bfloat16*)Cout)[(size_t)crow * ldc + ccol] = __float2bfloat16(v);
        } else {
          v += bias[ccol];
          size_t off = (size_t)crow * ldc + ccol;
#pragma unroll
          for (int p = 0; p < 6; ++p) v += red[redStride * p + off];
          ((float*)Cout)[off] = v;
        }
      }
    }
  }
}

// =================================================================
// Kernel 2: Wfused GEMM (long, first) + LSTM z GEMM in one dispatch.
// jobs [0,576):  Wfsum^T[1024,9216] = Btc[:,1024:4096] @ Wcat^T (K=3072,48 it)
// jobs [576,1088): z = A1 @ Bt1^T (M=2048,N=4096,K=2048, 32 it)
// =================================================================
__global__ __launch_bounds__(256) void gemm_multi(
    const __hip_bfloat16* __restrict__ A1, const __hip_bfloat16* __restrict__ Bt1,
    const __hip_bfloat16* __restrict__ Btc, const __hip_bfloat16* __restrict__ Wcat,
    float* __restrict__ z, __hip_bfloat16* __restrict__ Wfsum) {
  int id = blockIdx.x;
  if (id < 576) {
    int m0 = (id / 72) * 128;   // uo tiles: 8
    int n0 = (id % 72) * 128;   // kk tiles: 72
    gemm_core<1>(Btc + 1024, COMB_K, Wcat, WCAT_K, Wfsum, KAN_K,
                 m0, n0, 0, WCAT_K);
  } else {
    int j2 = id - 576;
    int n0 = (j2 & 31) * 128;
    int m0 = (j2 >> 5) * 128;
    gemm_core<0>(A1, LSTM_K, Bt1, LSTM_K, z, LSTM_N, m0, n0, 0, LSTM_K);
  }
}

// =================================================================
// Kernel 3: kan GEMM split-K=6 (first) + LSTM gates (backfill).
// jobs [0,768): Pkan[sk] = Akan @ Wfsum^T over K-chunk sk (1536 each, 24 it)
// jobs [768,8960): gates over B*U -> h, c, Hb(bf16)
// =================================================================
__global__ __launch_bounds__(256) void kan_gates(
    const __hip_bfloat16* __restrict__ Akan, const __hip_bfloat16* __restrict__ Wfsum,
    const float* __restrict__ z, const float* __restrict__ c_prev,
    const float* __restrict__ bias, float* __restrict__ Pkan,
    float* __restrict__ h_out, float* __restrict__ c_out,
    __hip_bfloat16* __restrict__ Hb) {
  int id = blockIdx.x;
  if (id < 768) {
    int sk = id >> 7;
    int rem = id & 127;
    int n0 = (rem & 7) * 128;   // uo tiles: 8
    int m0 = (rem >> 3) * 128;  // b tiles: 16
    gemm_core<0>(Akan, KAN_K, Wfsum, KAN_K, Pkan + (size_t)sk * B_SZ * U_SZ, U_SZ,
                 m0, n0, sk * 1536, sk * 1536 + 1536);
    return;
  }
  int idx = (id - 768) * 256 + threadIdx.x;  // over B*U
  int b = idx >> 10, u = idx & 1023;
  const float* zr = z + (size_t)b * LSTM_N;
  float zi = zr[u] + bias[u];
  float zf = zr[U_SZ + u] + bias[U_SZ + u];
  float zg = zr[2 * U_SZ + u] + bias[2 * U_SZ + u];
  float zo = zr[3 * U_SZ + u] + bias[3 * U_SZ + u];
  float c = fsig(zf) * c_prev[idx] + fsig(zi) * ftanh(zg);
  float h = fsig(zo) * ftanh(c);
  h_out[idx] = h;
  c_out[idx] = c;
  Hb[idx] = __float2bfloat16(h);
}

// =================================================================
// Kernel 4: h-GEMM (M=2048,N=1024,K=1024) with fused epilogue:
// out = h @ Wc_top + Σ_p Pkan[p] + bias
// =================================================================
__global__ __launch_bounds__(256) void final_gemm(
    const __hip_bfloat16* __restrict__ Hb, const __hip_bfloat16* __restrict__ Btc,
    const float* __restrict__ Pkan, const float* __restrict__ comb_b,
    float* __restrict__ out) {
  int id = blockIdx.x;  // 128 blocks
  int n0 = (id & 7) * 128;
  int m0 = (id >> 3) * 128;
  gemm_core<3>(Hb, U_SZ, Btc, COMB_K, out, U_SZ, m0, n0, 0, U_SZ,
               comb_b, Pkan, (size_t)B_SZ * U_SZ);
}

// ---------------- launcher ----------------
extern "C" void kernel_launch(void* const* d_in, const int* in_sizes, int n_in,
                              void* d_out, int out_size, void* d_ws, size_t ws_size,
                              hipStream_t stream) {
  const float* x        = (const float*)d_in[0];
  const float* h_prev   = (const float*)d_in[1];
  const float* c_prev   = (const float*)d_in[2];
  const float* lstm_k   = (const float*)d_in[3];
  const float* lstm_r   = (const float*)d_in[4];
  const float* lstm_b   = (const float*)d_in[5];
  const float* base_w   = (const float*)d_in[6];
  const float* spline_w = (const float*)d_in[7];
  const float* comb_w   = (const float*)d_in[8];
  const float* comb_b   = (const float*)d_in[9];
  float* out = (float*)d_out;  // [output | h | c], each B*U f32

  char* ws = (char*)d_ws;
  auto alloc = [&](size_t bytes) {
    char* p = ws;
    ws += (bytes + 255) & ~(size_t)255;
    return p;
  };
  __hip_bfloat16* A1    = (__hip_bfloat16*)alloc((size_t)B_SZ * LSTM_K * 2);   // 8MB
  __hip_bfloat16* Akan  = (__hip_bfloat16*)alloc((size_t)B_SZ * KAN_K * 2);    // 36MB
  __hip_bfloat16* Hb    = (__hip_bfloat16*)alloc((size_t)B_SZ * U_SZ * 2);     // 4MB
  __hip_bfloat16* Bt1   = (__hip_bfloat16*)alloc((size_t)LSTM_N * LSTM_K * 2); // 16MB
  __hip_bfloat16* Btc   = (__hip_bfloat16*)alloc((size_t)U_SZ * COMB_K * 2);   // 8MB
  __hip_bfloat16* Wcat  = (__hip_bfloat16*)alloc((size_t)KAN_K * WCAT_K * 2);  // 56.6MB
  __hip_bfloat16* Wfsum = (__hip_bfloat16*)alloc((size_t)U_SZ * KAN_K * 2);    // 18.9MB
  float* z              = (float*)alloc((size_t)B_SZ * LSTM_N * 4);            // 32MB
  float* Pkan           = (float*)alloc((size_t)6 * B_SZ * U_SZ * 4);          // 50.3MB

  // 1) prep + small transposes + Wcat interleave
  prep_trans<<<dim3(25088), 256, 0, stream>>>(x, h_prev, lstm_k, lstm_r, comb_w,
                                              base_w, spline_w, A1, Akan, Bt1, Btc, Wcat);
  // 2) Wfused GEMM + LSTM z GEMM
  gemm_multi<<<dim3(1088), 256, 0, stream>>>(A1, Bt1, Btc, Wcat, z, Wfsum);
  // 3) kan GEMM split-K=6 + gates
  kan_gates<<<dim3(8960), 256, 0, stream>>>(Akan, Wfsum, z, c_prev, lstm_b, Pkan,
                                            out + (size_t)B_SZ * U_SZ,
                                            out + 2 * (size_t)B_SZ * U_SZ, Hb);
  // 4) h-GEMM + partial-reduce + bias -> out
  final_gemm<<<dim3(128), 256, 0, stream>>>(Hb, Btc, Pkan, comb_b, out);
}